// Round 17
// baseline (492.123 us; speedup 1.0000x reference)
//
#include <hip/hip_runtime.h>
#include <math.h>

// ---------------------------------------------------------------------------
// XLSTMCell: gates = [x|h] @ W + b  (16384 x 5120 x 2048 GEMM, bf16 MFMA)
// R17: FULL register double-buffering — the one structure where NO wait sits
// between a tile's fragment reads and its MFMAs (shared flaw of all 9 prior
// variants pinned at 38-41% MfmaUtil: LDS 2260cy + MFMA 2483cy executed as a
// SUM under in-tile read->use waits).
//   BM=256 BN=128 BK=64, 8 waves 4Mx2N (64x64/wave), acc 64 + 2 frag sets
//   (af/bf x2) ~212 VGPR. 3-slot LDS ring (48 KB/slot = 144 KB).
//   Per tile kt: STAGE(kt+3 -> slot kt%3) | ds_read tile kt+1 -> set[cur^1]
//   | MFMA tile kt from set[cur] (disjoint regs => compiler interleaves
//   freely, lgkm waits land at NEXT tile's first use) | lgkmcnt(0) (WAR
//   proof) | vmcnt(6) (forces stage kt+2 landed for next tile's reads;
//   NEVER drains) | s_barrier.
//   WAR: slot kt%3's last reads (tile kt, during iter kt-1) completed before
//   iter kt-1's lgkm0+barrier. RAW: reads(kt+1) forced by iter kt-1's
//   vmcnt(6)+barrier. Stage->read lead = 2 tiles (~3500cy >> HBM 900cy).
// Pre-swizzled global (granule g of each 64-col window of row r at slot
// g^(r&7)) + linear global_load_lds (offset arg MUST be 0) + XOR'd ds_read
// = 0 bank conflicts (verified R4-R16). XCD L3-blocking (R13: FETCH -63%).
// Pre-commit: GEMM >= 380us -> practical ceiling, stop.
// ws layout: A_bf16[16384][2048] | Wt_bf16[5120][2048] | gates[16384][5120]
// ---------------------------------------------------------------------------

typedef unsigned short u16;
typedef unsigned int   u32;
typedef short  short8 __attribute__((ext_vector_type(8)));
typedef float  f32x4  __attribute__((ext_vector_type(4)));
typedef u16    u16x4  __attribute__((ext_vector_type(4)));
typedef u32    u32x4  __attribute__((ext_vector_type(4)));

#define B_ROWS 16384
#define K_DIM  2048
#define N_DIM  5120
#define H_DIM  1024

__device__ __forceinline__ float b2f(u16 u) {
    u32 v = ((u32)u) << 16;
    return __uint_as_float(v);
}
__device__ __forceinline__ u16 f2b(float f) {   // round-to-nearest-even
    u32 x = __float_as_uint(f);
    u32 r = (x + 0x7fffu + ((x >> 16) & 1u)) >> 16;
    return (u16)r;
}
__device__ __forceinline__ float sigm(float v) {
    return 1.f / (1.f + __expf(-v));
}
__device__ __forceinline__ float tanh_fast(float v) {
    v = fminf(fmaxf(v, -15.f), 15.f);
    float e = __expf(-2.f * v);
    return (1.f - e) / (1.f + e);
}

// ---------------------------------------------------------------------------
// 1) pack [x | h_prev] -> bf16 A [16384][2048], PRE-SWIZZLED:
//    granule slot s of each 64-elem K-window of row r holds granule s^(r&7).
// ---------------------------------------------------------------------------
__global__ __launch_bounds__(256) void convert_A(const float* __restrict__ x,
                                                 const float* __restrict__ h,
                                                 u16* __restrict__ A) {
    size_t idx = ((size_t)blockIdx.x * 256 + threadIdx.x) * 8;   // out elem idx
    int row = (int)(idx >> 11);
    int col = (int)(idx & 2047);                 // granule-aligned (col%8==0)
    int srcCol = (col & ~63) | (((((col >> 3) & 7) ^ (row & 7))) << 3);
    const float* src = (srcCol < 1024) ? (x + (size_t)row * 1024 + srcCol)
                                       : (h + (size_t)row * 1024 + (srcCol - 1024));
    f32x4 v0 = *(const f32x4*)src;
    f32x4 v1 = *(const f32x4*)(src + 4);
    u32x4 w;
    w.x = (u32)f2b(v0.x) | ((u32)f2b(v0.y) << 16);
    w.y = (u32)f2b(v0.z) | ((u32)f2b(v0.w) << 16);
    w.z = (u32)f2b(v1.x) | ((u32)f2b(v1.y) << 16);
    w.w = (u32)f2b(v1.z) | ((u32)f2b(v1.w) << 16);
    *(u32x4*)(A + idx) = w;
}

// ---------------------------------------------------------------------------
// 2) W [2048][5120] f32 -> Wt [5120][2048] bf16, transposed + PRE-SWIZZLED
//    (same granule rule, keyed by n-row & 7).
// ---------------------------------------------------------------------------
__global__ __launch_bounds__(256) void convert_W(const float* __restrict__ W,
                                                 u16* __restrict__ Wt) {
    __shared__ float tile[64][33];      // [k][n]
    const int t  = threadIdx.x;
    const int tx = t & 31;              // n
    const int ty = t >> 5;              // 0..7 (k)
    const int n0 = blockIdx.x * 32;     // 160 blocks
    const int k0 = blockIdx.y * 64;     // 32 blocks
#pragma unroll
    for (int i = 0; i < 8; ++i)
        tile[ty + 8 * i][tx] = W[(size_t)(k0 + ty + 8 * i) * N_DIM + n0 + tx];
    __syncthreads();
    const int n = t >> 3;               // 0..31
    const int s = t & 7;                // output granule slot
    const int g = s ^ (n & 7);          // source granule ((n0+n)&7 == n&7)
    u32x4 w;
    w.x = (u32)f2b(tile[g * 8 + 0][n]) | ((u32)f2b(tile[g * 8 + 1][n]) << 16);
    w.y = (u32)f2b(tile[g * 8 + 2][n]) | ((u32)f2b(tile[g * 8 + 3][n]) << 16);
    w.z = (u32)f2b(tile[g * 8 + 4][n]) | ((u32)f2b(tile[g * 8 + 5][n]) << 16);
    w.w = (u32)f2b(tile[g * 8 + 6][n]) | ((u32)f2b(tile[g * 8 + 7][n]) << 16);
    *(u32x4*)(Wt + (size_t)(n0 + n) * K_DIM + k0 + s * 8) = w;
}

// ---------------------------------------------------------------------------
// 3) GEMM: 256x128, BK=64, 512 thr (8 waves 4Mx2N), reg-double-buffered.
// ---------------------------------------------------------------------------
#define BK 64

__device__ __forceinline__ void gld_lds16(const void* g, void* l) {
    __builtin_amdgcn_global_load_lds(
        (const __attribute__((address_space(1))) void*)g,
        (__attribute__((address_space(3))) void*)l, 16, 0, 0);   // offset MUST be 0
}

__global__ __launch_bounds__(512, 1) void gemm_gates(const u16* __restrict__ A,
                                                     const u16* __restrict__ Bt,
                                                     const float* __restrict__ bias,
                                                     u16* __restrict__ gates) {
    // slot: A part [0..16384) u16 (256x64), B part [16384..24576) (128x64)
    __shared__ u16 lds[3][24576];         // 144 KiB

    const int t = threadIdx.x;
    // XCD L3-blocking: nwg = 2560 (%8==0). XCD x owns 8 m-blocks(256) x all
    // 40 n0(128); n outer, m inner.
    const int bid = blockIdx.x;
    const int xcd = bid & 7;
    const int c   = bid >> 3;             // 0..319
    const int m0 = ((xcd << 3) | (c & 7)) << 8;   // 64 m-blocks
    const int n0 = (c >> 3) << 7;                 // 40 n-blocks

    const int l   = t & 63;
    const int wid = t >> 6;
    const int wr  = wid >> 1;             // 0..3 (M)
    const int wc  = wid & 1;              // 0/1  (N)
    const int lr  = l & 15;
    const int lh  = l >> 4;
    const int z   = lr & 7;
    const int sA0 = (lh ^ z) * 8;         // sk=0 granule slot offset (u16)

    // staging: thread t -> row t>>3 of each 64-row stripe, granule t&7
    const u16* aBase = A  + (size_t)(m0 + (t >> 3)) * K_DIM + (t & 7) * 8;
    const u16* bBase = Bt + (size_t)(n0 + (t >> 3)) * K_DIM + (t & 7) * 8;
    const int dOff = t * 8;               // u16

    f32x4 acc[4][4] = {};
    short8 af[2][4][2], bf[2][4][2];      // [set][frag][ksub]
    u16* p0 = &lds[0][0];                 // stage target  (slot kt%3)
    u16* p1 = &lds[1][0];                 // read source   (slot (kt+1)%3)
    u16* p2 = &lds[2][0];                 // in-flight     (slot (kt+2)%3)

#define STAGE(P, OFF) do {                                                    \
    _Pragma("unroll") for (int i = 0; i < 4; ++i)                             \
        gld_lds16(aBase + (size_t)(i * 64) * K_DIM + (OFF),                   \
                  (P) + i * 4096 + dOff);                                     \
    _Pragma("unroll") for (int i = 0; i < 2; ++i)                             \
        gld_lds16(bBase + (size_t)(i * 64) * K_DIM + (OFF),                   \
                  (P) + 16384 + i * 4096 + dOff);                             \
} while (0)

#define RD(SET, P) do {                                                       \
    _Pragma("unroll") for (int m = 0; m < 4; ++m) {                           \
        const int u_ = (wr * 64 + m * 16 + lr) * 64;                          \
        af[SET][m][0] = *(const short8*)&(P)[u_ + sA0];                       \
        af[SET][m][1] = *(const short8*)&(P)[u_ + (sA0 ^ 32)];                \
    }                                                                         \
    _Pragma("unroll") for (int n = 0; n < 4; ++n) {                           \
        const int u_ = 16384 + (wc * 64 + n * 16 + lr) * 64;                  \
        bf[SET][n][0] = *(const short8*)&(P)[u_ + sA0];                       \
        bf[SET][n][1] = *(const short8*)&(P)[u_ + (sA0 ^ 32)];                \
    }                                                                         \
} while (0)

#define MFMA_T(SET) do {                                                      \
    __builtin_amdgcn_s_setprio(1);                                            \
    _Pragma("unroll") for (int sk = 0; sk < 2; ++sk)                          \
    _Pragma("unroll") for (int m = 0; m < 4; ++m)                             \
    _Pragma("unroll") for (int n = 0; n < 4; ++n)                             \
        acc[m][n] = __builtin_amdgcn_mfma_f32_16x16x32_bf16(                  \
            af[SET][m][sk], bf[SET][n][sk], acc[m][n], 0, 0, 0);              \
    __builtin_amdgcn_s_setprio(0);                                            \
} while (0)

    // One tile: stage kt+3 into p0 | read kt+1 from p1 into set CUR^1 |
    // MFMA tile kt from set CUR (no waits between: disjoint registers).
#define TILE(CUR, OFF) do {                                                   \
    STAGE(p0, OFF);                                                           \
    RD((CUR) ^ 1, p1);                                                        \
    MFMA_T(CUR);                                                              \
    asm volatile("s_waitcnt lgkmcnt(0)" ::: "memory");  /* WAR: reads done */ \
    asm volatile("s_waitcnt vmcnt(6)" ::: "memory");    /* kt+2 landed */     \
    __builtin_amdgcn_s_barrier();                                             \
    __builtin_amdgcn_sched_barrier(0);                                        \
    u16* tmp_ = p0; p0 = p1; p1 = p2; p2 = tmp_;        /* rotate ring */     \
} while (0)

    // prologue: stage tiles 0,1,2; vmcnt(6) -> tiles 0,1 landed; read tile 0.
    STAGE(p0, 0); STAGE(p1, 64); STAGE(p2, 128);
    asm volatile("s_waitcnt vmcnt(6)" ::: "memory");
    __builtin_amdgcn_s_barrier();
    __builtin_amdgcn_sched_barrier(0);
    RD(0, p0);                            // tile 0 -> set 0
    asm volatile("s_waitcnt lgkmcnt(0)" ::: "memory");
    __builtin_amdgcn_s_barrier();         // slot 0 free for first STAGE
    __builtin_amdgcn_sched_barrier(0);

    // 16 iters x 2 tiles = 32 tiles = K 2048.
#pragma unroll 1
    for (int it = 0; it < 16; ++it) {
        TILE(0, 192);                     // kt=2it:   stage 2it+3, read 2it+1
        TILE(1, 256);                     // kt=2it+1: stage 2it+4, read 2it+2
        aBase += 128;
        bBase += 128;
    }
    // tiles 32-34 staged / tile-32 read are in-ws garbage, never MFMA'd.

    asm volatile("s_waitcnt vmcnt(0)" ::: "memory");   // drain garbage stages

    // epilogue: bias + activation (block's N-tile lies in one gate group)
    const int grp = n0 >> 10;             // 0..4 : f,i,o,c,m
#pragma unroll
    for (int ni = 0; ni < 4; ++ni) {
        int col = n0 + wc * 64 + ni * 16 + lr;
        float bv = bias[col];
#pragma unroll
        for (int m = 0; m < 4; ++m) {
#pragma unroll
            for (int j = 0; j < 4; ++j) {
                int row = m0 + wr * 64 + m * 16 + lh * 4 + j;
                float v = acc[m][ni][j] + bv;
                float g = (grp == 3) ? tanh_fast(v) : sigm(v);
                gates[(size_t)row * N_DIM + col] = f2b(g);
            }
        }
    }
#undef STAGE
#undef RD
#undef MFMA_T
#undef TILE
}

// ---------------------------------------------------------------------------
// 4) per-row: LN stats over o, cell update, outputs (R13 version)
// ---------------------------------------------------------------------------
__global__ __launch_bounds__(256) void fuse_out(const u16* __restrict__ gates,
                                                const float* __restrict__ c_prev,
                                                const float* __restrict__ ret,
                                                const float* __restrict__ gamma,
                                                const float* __restrict__ beta,
                                                float* __restrict__ out) {
    const int r = blockIdx.x;
    const int t = threadIdx.x;
    const u16* g = gates + (size_t)r * N_DIM;
    const int j0 = t * 4;

    // o = sigmoid(o_pre) already; LN stats over the row of 1024
    u16x4 ov = *(const u16x4*)(g + 2048 + j0);
    float o0 = b2f(ov.x), o1 = b2f(ov.y), o2 = b2f(ov.z), o3 = b2f(ov.w);
    float s1 = o0 + o1 + o2 + o3;
    float s2 = o0 * o0 + o1 * o1 + o2 * o2 + o3 * o3;
#pragma unroll
    for (int off = 32; off; off >>= 1) {
        s1 += __shfl_xor(s1, off, 64);
        s2 += __shfl_xor(s2, off, 64);
    }
    __shared__ float red[8];
    if ((t & 63) == 0) { red[t >> 6] = s1; red[4 + (t >> 6)] = s2; }
    __syncthreads();
    float S1 = red[0] + red[1] + red[2] + red[3];
    float S2 = red[4] + red[5] + red[6] + red[7];
    float mu   = S1 * (1.f / 1024.f);
    float var  = S2 * (1.f / 1024.f) - mu * mu;
    float rstd = rsqrtf(var + 1e-5f);

    u16x4 fv = *(const u16x4*)(g + j0);
    u16x4 iv = *(const u16x4*)(g + 1024 + j0);
    u16x4 cv = *(const u16x4*)(g + 3072 + j0);
    u16x4 mv = *(const u16x4*)(g + 4096 + j0);
    f32x4 cp = *(const f32x4*)(c_prev + (size_t)r * H_DIM + j0);
    f32x4 rt = *(const f32x4*)(ret + j0);
    f32x4 gm = *(const f32x4*)(gamma + j0);
    f32x4 bt = *(const f32x4*)(beta + j0);

    float of[4] = {o0, o1, o2, o3};
    u16 fa[4] = {fv.x, fv.y, fv.z, fv.w};
    u16 ia[4] = {iv.x, iv.y, iv.z, iv.w};
    u16 ca[4] = {cv.x, cv.y, cv.z, cv.w};
    u16 ma[4] = {mv.x, mv.y, mv.z, mv.w};

    f32x4 hout, cout;
#pragma unroll
    for (int i = 0; i < 4; ++i) {
        float f = b2f(fa[i]), ig = b2f(ia[i]), cc = b2f(ca[i]), m = b2f(ma[i]);
        float cpv = cp[i], rv = rt[i];
        float c1 = f * cpv + ig * cc;
        float c2 = c1 * rv + (1.f - rv) * cpv;
        float cn = m * c2 + (1.f - m) * cpv;
        float ln = (of[i] - mu) * rstd * gm[i] + bt[i];
        float oe = sigm(ln);
        float hn = oe * tanh_fast(cn);
        hout[i] = hn;
        cout[i] = cn;
    }
    *(f32x4*)(out + (size_t)r * H_DIM + j0) = hout;
    *(f32x4*)(out + (size_t)B_ROWS * H_DIM + (size_t)r * H_DIM + j0) = cout;
}

// ---------------------------------------------------------------------------
extern "C" void kernel_launch(void* const* d_in, const int* in_sizes, int n_in,
                              void* d_out, int out_size, void* d_ws, size_t ws_size,
                              hipStream_t stream) {
    const float* x      = (const float*)d_in[0];
    const float* h_prev = (const float*)d_in[1];
    const float* c_prev = (const float*)d_in[2];
    const float* W      = (const float*)d_in[3];
    const float* bias   = (const float*)d_in[4];
    const float* gamma  = (const float*)d_in[5];
    const float* beta   = (const float*)d_in[6];
    const float* ret    = (const float*)d_in[7];
    float* out = (float*)d_out;

    u16* Abuf  = (u16*)d_ws;                             // [16384][2048]
    u16* Wt    = Abuf + (size_t)B_ROWS * K_DIM;          // [5120][2048]
    u16* gates = Wt + (size_t)N_DIM * K_DIM;             // [16384][5120]

    convert_A<<<(B_ROWS * K_DIM / 8) / 256, 256, 0, stream>>>(x, h_prev, Abuf);
    convert_W<<<dim3(N_DIM / 32, K_DIM / 64), 256, 0, stream>>>(W, Wt);
    gemm_gates<<<(B_ROWS / 256) * (N_DIM / 128), 512, 0, stream>>>(Abuf, Wt, bias, gates);
    fuse_out<<<B_ROWS, 256, 0, stream>>>(gates, c_prev, ret, gamma, beta, out);
}